// Round 7
// baseline (233.132 us; speedup 1.0000x reference)
//
#include <hip/hip_runtime.h>
#include <hip/hip_bf16.h>
#include <math.h>

#define B_ 8
#define N_ 8192
#define D_ 512
#define G_ 64
#define M_ (B_ * N_)   // 65536

typedef short bf16x8 __attribute__((ext_vector_type(8)));
typedef float f32x4 __attribute__((ext_vector_type(4)));

__device__ __forceinline__ unsigned short f2bf(float f) {
    __hip_bfloat16 h = __float2bfloat16(f);
    return *reinterpret_cast<unsigned short*>(&h);
}
__device__ __forceinline__ void gload_lds16(const void* g, void* l) {
    __builtin_amdgcn_global_load_lds((const __attribute__((address_space(1))) void*)g,
                                     (__attribute__((address_space(3))) void*)l,
                                     16, 0, 0);
}
// un-sinkable 16B global load: volatile asm is pinned at its source position
__device__ __forceinline__ void gl_f32x4(f32x4& dst, const float* p) {
    asm volatile("global_load_dwordx4 %0, %1, off"
                 : "=v"(dst) : "v"(p) : "memory");
}

// ---------------- cast kernel (weights only; x is consumed f32 directly) ----
__global__ __launch_bounds__(256) void cast_w(const float* __restrict__ w1,
                                              const float* __restrict__ b1,
                                              const float* __restrict__ w2,
                                              const float* __restrict__ b2,
                                              unsigned short* __restrict__ wB,
                                              float* __restrict__ biasB) {
    int t = blockIdx.x * 256 + threadIdx.x;   // 0..131071, one float4
    int idx = t * 4;
    int row = idx >> 9;
    int col = idx & 511;
    const float* src = (row < 512) ? (w1 + (size_t)row * 512 + col)
                                   : (w2 + (size_t)(row - 512) * 512 + col);
    float4 f = *(const float4*)src;
    ushort4 u;
    u.x = f2bf(f.x); u.y = f2bf(f.y); u.z = f2bf(f.z); u.w = f2bf(f.w);
    *(ushort4*)(wB + idx) = u;
    if (t < 1024) biasB[t] = (t < 512) ? b1[t] : b2[t - 512];
}

// ---------------- group-sorted permutation, bases, tile->first-group --------
__global__ __launch_bounds__(256) void build_lists3(const int* __restrict__ ids,
                                                    int* __restrict__ counts,
                                                    int* __restrict__ baseO,
                                                    int* __restrict__ fgO,
                                                    int* __restrict__ perm) {
    __shared__ int sid[N_];                    // 32 KB
    __shared__ unsigned short hist[256][G_];   // 32 KB
    __shared__ int sbase[G_ + 1];
    const int t = threadIdx.x;
    for (int i = t; i < N_; i += 256) sid[i] = ids[i];
#pragma unroll
    for (int g = 0; g < G_; ++g) hist[t][g] = 0;
    __syncthreads();
    const int nb = t * 32;
    for (int k = 0; k < 32; ++k) hist[t][sid[nb + k]]++;
    __syncthreads();
    if (t < G_) {   // column-wise prefix over thread strips for group t
        int run = 0;
        for (int i = 0; i < 256; ++i) {
            int v = hist[i][t];
            hist[i][t] = (unsigned short)run;
            run += v;
        }
        counts[t] = run;
    }
    __syncthreads();
    if (t == 0) {
        int acc = 0;
        for (int g = 0; g < G_; ++g) { sbase[g] = acc; acc += counts[g]; }
        sbase[G_] = acc;
    }
    __syncthreads();
    if (t < G_) baseO[t] = sbase[t];
    if (t < G_) {   // first group of each 128-row tile
        const int row = t * 128;
        int g = 0;
        while (g + 1 < G_ && sbase[g + 1] <= row) ++g;
        fgO[t] = g;
    }
    // emit permutation (deterministic: strip order, then in-strip order)
    for (int k = 0; k < 32; ++k) {
        const int n = nb + k;
        const int g = sid[n];
        const int pos = sbase[g] + hist[t][g];
        hist[t][g]++;
        perm[pos] = n;
    }
}

// ---------------- fused GEMM + segment softmax-aggregate --------------------
// Per block: 128 permuted rows (one b, one tile) x 64 e-cols.
// A reg-staged from f32 x via INLINE-ASM loads (un-sinkable; R5/R6's compiler
// sank builtin loads to their use -> exposed latency, VGPR stayed 88).
// Counted s_waitcnt vmcnt(4) waits only the A loads; B gload_lds stay in
// flight across writeA. sched_barrier(0) after the wait per rule 18.
__global__ __launch_bounds__(256) void gemm_fused(const float* __restrict__ x,
                                                  const unsigned short* __restrict__ wB,
                                                  const float* __restrict__ biasB,
                                                  const int* __restrict__ perm,
                                                  const int* __restrict__ base,
                                                  const int* __restrict__ fg,
                                                  float* __restrict__ pt) {
    __shared__ unsigned short lsA[2][128 * 64];    // 2 x 16 KB
    __shared__ unsigned short lsB[2][2][64 * 64];  // 2 x 2 x 8 KB   (W1, W2 panels)

    // block swizzle: 8 et-blocks sharing an A-tile are same-XCD, 8 apart
    const int o  = blockIdx.x;            // 0..4095
    const int mt = (o & 7) + ((o >> 6) << 3);   // 0..511 global m-tile
    const int et = (o >> 3) & 7;                // 0..7 e-tile (64 cols)
    const int b  = mt >> 6;
    const int tl = mt & 63;
    const int r0 = tl * 128;              // perm-slab row base

    const int tid = threadIdx.x;
    const int l = tid & 63;
    const int w = tid >> 6;
    const int wm = w >> 1, wn = w & 1;    // 2x2 wave grid: rows 64, cols 32
    const int lr = l >> 3;                // staging row-in-chunk
    const int lslot = l & 7;              // staging 16B slot
    const int fr = l & 15;                // fragment row/col
    const int scol = 8 * (lslot ^ lr);    // pre-swizzled source col (elems)

    // per-lane permuted A source rows (fixed across K)
    int nrow[4];
#pragma unroll
    for (int q = 0; q < 4; ++q) nrow[q] = perm[r0 + (w * 4 + q) * 8 + lr];

    f32x4 acc_a[4][2], acc_v[4][2];
#pragma unroll
    for (int i = 0; i < 4; ++i)
#pragma unroll
        for (int j = 0; j < 2; ++j) {
            acc_a[i][j] = (f32x4){0.f, 0.f, 0.f, 0.f};
            acc_v[i][j] = (f32x4){0.f, 0.f, 0.f, 0.f};
        }

    f32x4 areg[8];
    auto loadA = [&](int kt) {   // issue 8 pinned global f32x4 loads for tile kt
#pragma unroll
        for (int q = 0; q < 4; ++q) {
            const float* src = x + (((size_t)(b << 13) + nrow[q]) << 9) + kt + scol;
            gl_f32x4(areg[q * 2],     src);
            gl_f32x4(areg[q * 2 + 1], src + 4);
        }
    };
    auto writeA = [&](int buf) { // cvt + swizzled ds_write (same image as gload_lds)
#pragma unroll
        for (int q = 0; q < 4; ++q) {
            const int c = w * 4 + q;
            union { unsigned short us[8]; uint4 v4; } pk;
            const float* f = (const float*)&areg[q * 2];
#pragma unroll
            for (int e = 0; e < 8; ++e) pk.us[e] = f2bf(f[e]);
            *(uint4*)((char*)&lsA[buf][0] + c * 1024 + l * 16) = pk.v4;
        }
    };
    auto stageB = [&](int buf, int kt) {
#pragma unroll
        for (int q = 0; q < 4; ++q) {
            const int p = q >> 1;
            const int c2 = (w << 1) | (q & 1);
            const int wr = p * 512 + et * 64 + c2 * 8 + lr;
            gload_lds16(wB + ((size_t)wr << 9) + kt + scol, &lsB[buf][p][c2 * 512]);
        }
    };

    // prologue: issue A+B for tile 0, wait only A, write, barrier
    loadA(0);
    stageB(0, 0);
    asm volatile("s_waitcnt vmcnt(4)" ::: "memory");
    __builtin_amdgcn_sched_barrier(0);
    writeA(0);
    __syncthreads();
    int cur = 0;
    for (int t = 0; t < 8; ++t) {
        if (t < 7) { loadA((t + 1) * 64); stageB(cur ^ 1, (t + 1) * 64); }
#pragma unroll
        for (int ks = 0; ks < 2; ++ks) {
            const int ib = 8 * ((ks * 4 + (l >> 4)) ^ (fr & 7));   // swizzled in-row elems
            bf16x8 af[4], bq[2][2];
#pragma unroll
            for (int i = 0; i < 4; ++i)
                af[i] = *(const bf16x8*)&lsA[cur][(wm * 64 + i * 16 + fr) * 64 + ib];
#pragma unroll
            for (int p = 0; p < 2; ++p)
#pragma unroll
                for (int j = 0; j < 2; ++j)
                    bq[p][j] = *(const bf16x8*)&lsB[cur][p][(wn * 32 + j * 16 + fr) * 64 + ib];
#pragma unroll
            for (int i = 0; i < 4; ++i)
#pragma unroll
                for (int j = 0; j < 2; ++j) {
                    acc_a[i][j] = __builtin_amdgcn_mfma_f32_16x16x32_bf16(af[i], bq[0][j], acc_a[i][j], 0, 0, 0);
                    acc_v[i][j] = __builtin_amdgcn_mfma_f32_16x16x32_bf16(af[i], bq[1][j], acc_v[i][j], 0, 0, 0);
                }
        }
        if (t < 7) {
            asm volatile("s_waitcnt vmcnt(4)" ::: "memory");   // A loads done; B stay in flight
            __builtin_amdgcn_sched_barrier(0);                 // rule 18: no hoist of cvt above wait
            writeA(cur ^ 1);
        }
        __syncthreads();
        cur ^= 1;
    }

    // ---- epilogue: exp + segment reduce ----
    const int fg0 = fg[tl];
    const int bnd0 = (fg0 + 1 < G_) ? base[fg0 + 1] : (1 << 30);
    const int bnd1 = (fg0 + 2 < G_) ? base[fg0 + 2] : (1 << 30);
    const int bnd2 = (fg0 + 3 < G_) ? base[fg0 + 3] : (1 << 30);
    float b1c[2], b2c[2];
#pragma unroll
    for (int j = 0; j < 2; ++j) {
        const int col = et * 64 + wn * 32 + j * 16 + fr;
        b1c[j] = biasB[col];
        b2c[j] = biasB[512 + col];
    }
    float dpart[4][2] = {}, ypart[4][2] = {};
    const int rbase = r0 + wm * 64 + ((l >> 4) << 2);
#pragma unroll
    for (int i = 0; i < 4; ++i)
#pragma unroll
        for (int rr = 0; rr < 4; ++rr) {
            const int row = rbase + i * 16 + rr;
            const int s = (row >= bnd0) + (row >= bnd1) + (row >= bnd2);
#pragma unroll
            for (int j = 0; j < 2; ++j) {
                const float e = __expf(acc_a[i][j][rr] + b1c[j]);
                const float ey = e * (acc_v[i][j][rr] + b2c[j]);
#pragma unroll
                for (int s2 = 0; s2 < 4; ++s2) {
                    dpart[s2][j] += (s == s2) ? e : 0.f;
                    ypart[s2][j] += (s == s2) ? ey : 0.f;
                }
            }
        }
    // butterfly over lane bits 4,5 -> sum over the wave's 64 rows
#pragma unroll
    for (int s2 = 0; s2 < 4; ++s2)
#pragma unroll
        for (int j = 0; j < 2; ++j) {
            dpart[s2][j] += __shfl_xor(dpart[s2][j], 16);
            dpart[s2][j] += __shfl_xor(dpart[s2][j], 32);
            ypart[s2][j] += __shfl_xor(ypart[s2][j], 16);
            ypart[s2][j] += __shfl_xor(ypart[s2][j], 32);
        }
    float* red = (float*)&lsA[0][0];    // [wm][s][col64][2] = 4 KB
    if ((l >> 4) == 0) {
#pragma unroll
        for (int s2 = 0; s2 < 4; ++s2)
#pragma unroll
            for (int j = 0; j < 2; ++j) {
                const int colL = wn * 32 + j * 16 + fr;
                red[((wm * 4 + s2) * 64 + colL) * 2 + 0] = dpart[s2][j];
                red[((wm * 4 + s2) * 64 + colL) * 2 + 1] = ypart[s2][j];
            }
    }
    __syncthreads();
#pragma unroll
    for (int k = 0; k < 2; ++k) {
        const int idx = tid * 2 + k;      // 0..511
        const int dy = idx & 1;
        const int colL = (idx >> 1) & 63;
        const int s2 = idx >> 7;
        const float vsum = red[((0 * 4 + s2) * 64 + colL) * 2 + dy] +
                           red[((1 * 4 + s2) * 64 + colL) * 2 + dy];
        pt[((((size_t)(b * 64 + tl)) * 4 + s2) * 512 + et * 64 + colL) * 2 + dy] = vsum;
    }
}

// ---------------- ordered cross-tile combine -> y[b][g][col] ----------------
__global__ __launch_bounds__(256) void combineC(const float* __restrict__ pt,
                                                const int* __restrict__ base,
                                                const int* __restrict__ counts,
                                                const int* __restrict__ fg,
                                                float* __restrict__ y) {
    const int g = blockIdx.x, b = blockIdx.y;
    const int bs = base[g];
    int cnt = counts[g];
    if (cnt == 0) cnt = 1;
    const int t0 = bs >> 7, t1 = (bs + cnt - 1) >> 7;
    for (int c = threadIdx.x; c < 512; c += 256) {
        float d = 0.f, yy = 0.f;
        for (int t = t0; t <= t1; ++t) {
            const int s = g - fg[t];
            if (s >= 0 && s < 4) {
                const float* p = &pt[((((size_t)(b * 64 + t)) * 4 + s) * 512 + c) * 2];
                d += p[0];
                yy += p[1];
            }
        }
        y[((size_t)(b * G_ + g)) * 512 + c] = yy / d;
    }
}

// ---------------- small GEMM: out_small = y @ w3^T + b3 (f32 vector) --------
__global__ __launch_bounds__(256) void gemm3(const float* __restrict__ y,
                                             const float* __restrict__ w3,
                                             const float* __restrict__ b3,
                                             float* __restrict__ out_small) {
    __shared__ float ys[16][68];
    __shared__ float wss[16][68];
    const int m0 = blockIdx.x * 64;
    const int n0 = blockIdx.y * 64;
    const int tid = threadIdx.x;
    const int tr = tid >> 4;
    const int tc = tid & 15;
    const int lrow = tid >> 2;
    const int lk4 = (tid & 3) * 4;

    float acc[4][4] = {};

    for (int k0 = 0; k0 < D_; k0 += 16) {
        float4 yv = *(const float4*)(y + (size_t)(m0 + lrow) * D_ + k0 + lk4);
        float4 wv = *(const float4*)(w3 + (size_t)(n0 + lrow) * D_ + k0 + lk4);
        __syncthreads();
        ys[lk4 + 0][lrow] = yv.x;  ys[lk4 + 1][lrow] = yv.y;
        ys[lk4 + 2][lrow] = yv.z;  ys[lk4 + 3][lrow] = yv.w;
        wss[lk4 + 0][lrow] = wv.x; wss[lk4 + 1][lrow] = wv.y;
        wss[lk4 + 2][lrow] = wv.z; wss[lk4 + 3][lrow] = wv.w;
        __syncthreads();
#pragma unroll
        for (int kk = 0; kk < 16; ++kk) {
            float4 y4 = *(const float4*)&ys[kk][tr * 4];
            float4 w4 = *(const float4*)&wss[kk][tc * 4];
            float ya[4] = {y4.x, y4.y, y4.z, y4.w};
            float wa[4] = {w4.x, w4.y, w4.z, w4.w};
#pragma unroll
            for (int i = 0; i < 4; ++i)
#pragma unroll
                for (int j = 0; j < 4; ++j)
                    acc[i][j] = fmaf(ya[i], wa[j], acc[i][j]);
        }
    }

    float bb[4];
#pragma unroll
    for (int j = 0; j < 4; ++j) bb[j] = b3[n0 + tc * 4 + j];
#pragma unroll
    for (int i = 0; i < 4; ++i) {
        size_t o = (size_t)(m0 + tr * 4 + i) * D_ + n0 + tc * 4;
        float4 r;
        r.x = acc[i][0] + bb[0]; r.y = acc[i][1] + bb[1];
        r.z = acc[i][2] + bb[2]; r.w = acc[i][3] + bb[3];
        *(float4*)(out_small + o) = r;
    }
}

// ---------------- gather group outputs back to rows -------------------------
__global__ __launch_bounds__(256) void gather_out(const int* __restrict__ ids,
                                                  const float* __restrict__ out_small,
                                                  float* __restrict__ out) {
    const int c = blockIdx.x * 256 + threadIdx.x;   // one float4 chunk
    const int per_row = D_ / 4;                     // 128
    const int b = c / (N_ * per_row);
    const int rem = c % (N_ * per_row);
    const int n = rem / per_row;
    const int q = rem % per_row;
    const int g = ids[n];
    float4 val = *(const float4*)(out_small + ((size_t)b * G_ + g) * D_ + q * 4);
    *(float4*)(out + (size_t)c * 4) = val;
}

// ---------------- launcher --------------------------------------------------
extern "C" void kernel_launch(void* const* d_in, const int* in_sizes, int n_in,
                              void* d_out, int out_size, void* d_ws, size_t ws_size,
                              hipStream_t stream) {
    (void)in_sizes; (void)n_in; (void)out_size; (void)ws_size;
    const float* x   = (const float*)d_in[0];
    const int*   ids = (const int*)d_in[1];
    const float* w1  = (const float*)d_in[2];
    const float* b1  = (const float*)d_in[3];
    const float* w2  = (const float*)d_in[4];
    const float* b2  = (const float*)d_in[5];
    const float* w3  = (const float*)d_in[6];
    const float* b3  = (const float*)d_in[7];
    float* out = (float*)d_out;

    float* ws_f = (float*)d_ws;
    unsigned short* wB = (unsigned short*)ws_f;          // 1 MB
    float* biasB     = ws_f + 262144;                    // 4 KB
    float* pt        = biasB + 1024;                     // 8 MB  [b][tl][s4][512][2]
    float* y         = pt + 2097152;                     // 1 MB
    float* out_small = y + 262144;                       // 1 MB
    int*   perm      = (int*)(out_small + 262144);       // 32 KB
    int*   base      = perm + N_;
    int*   counts    = base + G_;
    int*   fg        = counts + G_;

    hipLaunchKernelGGL(cast_w, dim3(512), dim3(256), 0, stream, w1, b1, w2, b2, wB, biasB);
    hipLaunchKernelGGL(build_lists3, dim3(1), dim3(256), 0, stream, ids, counts, base, fg, perm);
    hipLaunchKernelGGL(gemm_fused, dim3(4096), dim3(256), 0, stream,
                       x, wB, biasB, perm, base, fg, pt);
    hipLaunchKernelGGL(combineC, dim3(G_, B_), dim3(256), 0, stream, pt, base, counts, fg, y);
    hipLaunchKernelGGL(gemm3, dim3(8, 8), dim3(256), 0, stream, y, w3, b3, out_small);
    hipLaunchKernelGGL(gather_out, dim3(32768), dim3(256), 0, stream, ids, out_small, out);
}

// Round 8
// 223.187 us; speedup vs baseline: 1.0446x; 1.0446x over previous
//
#include <hip/hip_runtime.h>
#include <hip/hip_bf16.h>
#include <math.h>

#define B_ 8
#define N_ 8192
#define D_ 512
#define G_ 64
#define M_ (B_ * N_)   // 65536

typedef short bf16x8 __attribute__((ext_vector_type(8)));
typedef float f32x4 __attribute__((ext_vector_type(4)));

__device__ __forceinline__ unsigned short f2bf(float f) {
    __hip_bfloat16 h = __float2bfloat16(f);
    return *reinterpret_cast<unsigned short*>(&h);
}
__device__ __forceinline__ void gload_lds16(const void* g, void* l) {
    __builtin_amdgcn_global_load_lds((const __attribute__((address_space(1))) void*)g,
                                     (__attribute__((address_space(3))) void*)l,
                                     16, 0, 0);
}

// ---------------- permuted cast: xb[b][i][:] = bf16(x[b][perm[i]][:]) -------
__global__ __launch_bounds__(256) void cast_xp(const float* __restrict__ x,
                                               const int* __restrict__ perm,
                                               unsigned short* __restrict__ xb) {
    const int total = M_ * 128;          // one float4 per item
    for (int idx = blockIdx.x * 256 + threadIdx.x; idx < total;
         idx += gridDim.x * 256) {
        const int row = idx >> 7;        // 0..65535  (b*8192 + permuted slot)
        const int q = (idx & 127) * 4;
        const int b = row >> 13;
        const int i = row & 8191;
        const float* src = x + (((size_t)(b << 13) + perm[i]) << 9) + q;
        float4 f = *(const float4*)src;
        ushort4 u;
        u.x = f2bf(f.x); u.y = f2bf(f.y); u.z = f2bf(f.z); u.w = f2bf(f.w);
        *(ushort4*)(xb + ((size_t)row << 9) + q) = u;
    }
}

// ---------------- cast kernel (weights) -------------------------------------
__global__ __launch_bounds__(256) void cast_w(const float* __restrict__ w1,
                                              const float* __restrict__ b1,
                                              const float* __restrict__ w2,
                                              const float* __restrict__ b2,
                                              unsigned short* __restrict__ wB,
                                              float* __restrict__ biasB) {
    int t = blockIdx.x * 256 + threadIdx.x;   // 0..131071, one float4
    int idx = t * 4;
    int row = idx >> 9;
    int col = idx & 511;
    const float* src = (row < 512) ? (w1 + (size_t)row * 512 + col)
                                   : (w2 + (size_t)(row - 512) * 512 + col);
    float4 f = *(const float4*)src;
    ushort4 u;
    u.x = f2bf(f.x); u.y = f2bf(f.y); u.z = f2bf(f.z); u.w = f2bf(f.w);
    *(ushort4*)(wB + idx) = u;
    if (t < 1024) biasB[t] = (t < 512) ? b1[t] : b2[t - 512];
}

// ---------------- group-sorted permutation, bases, tile->first-group --------
__global__ __launch_bounds__(256) void build_lists3(const int* __restrict__ ids,
                                                    int* __restrict__ counts,
                                                    int* __restrict__ baseO,
                                                    int* __restrict__ fgO,
                                                    int* __restrict__ perm) {
    __shared__ int sid[N_];                    // 32 KB
    __shared__ unsigned short hist[256][G_];   // 32 KB
    __shared__ int sbase[G_ + 1];
    const int t = threadIdx.x;
    for (int i = t; i < N_; i += 256) sid[i] = ids[i];
#pragma unroll
    for (int g = 0; g < G_; ++g) hist[t][g] = 0;
    __syncthreads();
    const int nb = t * 32;
    for (int k = 0; k < 32; ++k) hist[t][sid[nb + k]]++;
    __syncthreads();
    if (t < G_) {   // column-wise prefix over thread strips for group t
        int run = 0;
        for (int i = 0; i < 256; ++i) {
            int v = hist[i][t];
            hist[i][t] = (unsigned short)run;
            run += v;
        }
        counts[t] = run;
    }
    __syncthreads();
    if (t == 0) {
        int acc = 0;
        for (int g = 0; g < G_; ++g) { sbase[g] = acc; acc += counts[g]; }
        sbase[G_] = acc;
    }
    __syncthreads();
    if (t < G_) baseO[t] = sbase[t];
    if (t < G_) {   // first group of each 128-row tile
        const int row = t * 128;
        int g = 0;
        while (g + 1 < G_ && sbase[g + 1] <= row) ++g;
        fgO[t] = g;
    }
    // emit permutation (deterministic: strip order, then in-strip order)
    for (int k = 0; k < 32; ++k) {
        const int n = nb + k;
        const int g = sid[n];
        const int pos = sbase[g] + hist[t][g];
        hist[t][g]++;
        perm[pos] = n;
    }
}

// ---------------- fused GEMM + segment softmax-aggregate --------------------
// m97 regime: single-buffered 32KB LDS (5 blocks/CU), all staging via
// global_load_lds width=16 with pre-swizzled source cols; XCD-aware block
// swizzle; epilogue = exp + in-block segment reduce -> 8MB partials.
// A rows are already permuted (cast_xp), so staging is sequential.
__global__ __launch_bounds__(256) void gemm_fused(const unsigned short* __restrict__ xb,
                                                  const unsigned short* __restrict__ wB,
                                                  const float* __restrict__ biasB,
                                                  const int* __restrict__ base,
                                                  const int* __restrict__ fg,
                                                  float* __restrict__ pt) {
    __shared__ unsigned short lsA[128 * 64];    // 16 KB
    __shared__ unsigned short lsB[2][64 * 64];  // 2 x 8 KB   (W1, W2 panels)

    // block swizzle: 8 et-blocks sharing an A-tile are same-XCD, 8 apart
    const int o  = blockIdx.x;            // 0..4095
    const int mt = (o & 7) + ((o >> 6) << 3);   // 0..511 global m-tile
    const int et = (o >> 3) & 7;                // 0..7 e-tile (64 cols)
    const int b  = mt >> 6;
    const int tl = mt & 63;
    const int r0 = tl * 128;              // permuted-row base within batch

    const int tid = threadIdx.x;
    const int l = tid & 63;
    const int w = tid >> 6;
    const int wm = w >> 1, wn = w & 1;    // 2x2 wave grid: rows 64, cols 32
    const int lr = l >> 3;                // staging row-in-chunk
    const int lslot = l & 7;              // staging 16B slot
    const int fr = l & 15;                // fragment row/col
    const int scol = 8 * (lslot ^ lr);    // pre-swizzled source col (elems)

    f32x4 acc_a[4][2], acc_v[4][2];
#pragma unroll
    for (int i = 0; i < 4; ++i)
#pragma unroll
        for (int j = 0; j < 2; ++j) {
            acc_a[i][j] = (f32x4){0.f, 0.f, 0.f, 0.f};
            acc_v[i][j] = (f32x4){0.f, 0.f, 0.f, 0.f};
        }

    const size_t abase = ((size_t)(b << 13) + r0) << 9;   // xb row base (elems)

    for (int t = 0; t < 8; ++t) {
        const int kt = t * 64;
        // ---- stage A (4 chunks/wave) + B (4 chunks/wave) ----
#pragma unroll
        for (int q = 0; q < 4; ++q) {
            const int c = w * 4 + q;
            const int row = c * 8 + lr;
            gload_lds16(xb + abase + ((size_t)row << 9) + kt + scol, &lsA[c * 512]);
        }
#pragma unroll
        for (int q = 0; q < 4; ++q) {
            const int p = q >> 1;
            const int c2 = (w << 1) | (q & 1);
            const int wr = p * 512 + et * 64 + c2 * 8 + lr;
            gload_lds16(wB + ((size_t)wr << 9) + kt + scol, &lsB[p][c2 * 512]);
        }
        __syncthreads();   // drains vmcnt -> LDS valid
        // ---- compute: 2 k-subs of 32 ----
#pragma unroll
        for (int ks = 0; ks < 2; ++ks) {
            const int ib = 8 * ((ks * 4 + (l >> 4)) ^ (fr & 7));   // swizzled in-row elems
            bf16x8 af[4], bq[2][2];
#pragma unroll
            for (int i = 0; i < 4; ++i)
                af[i] = *(const bf16x8*)&lsA[(wm * 64 + i * 16 + fr) * 64 + ib];
#pragma unroll
            for (int p = 0; p < 2; ++p)
#pragma unroll
                for (int j = 0; j < 2; ++j)
                    bq[p][j] = *(const bf16x8*)&lsB[p][(wn * 32 + j * 16 + fr) * 64 + ib];
#pragma unroll
            for (int i = 0; i < 4; ++i)
#pragma unroll
                for (int j = 0; j < 2; ++j) {
                    acc_a[i][j] = __builtin_amdgcn_mfma_f32_16x16x32_bf16(af[i], bq[0][j], acc_a[i][j], 0, 0, 0);
                    acc_v[i][j] = __builtin_amdgcn_mfma_f32_16x16x32_bf16(af[i], bq[1][j], acc_v[i][j], 0, 0, 0);
                }
        }
        __syncthreads();   // everyone done reading before next stage overwrites
    }

    // ---- epilogue: exp + segment reduce ----
    const int fg0 = fg[tl];
    const int bnd0 = (fg0 + 1 < G_) ? base[fg0 + 1] : (1 << 30);
    const int bnd1 = (fg0 + 2 < G_) ? base[fg0 + 2] : (1 << 30);
    const int bnd2 = (fg0 + 3 < G_) ? base[fg0 + 3] : (1 << 30);
    float b1c[2], b2c[2];
#pragma unroll
    for (int j = 0; j < 2; ++j) {
        const int col = et * 64 + wn * 32 + j * 16 + fr;
        b1c[j] = biasB[col];
        b2c[j] = biasB[512 + col];
    }
    float dpart[4][2] = {}, ypart[4][2] = {};
    const int rbase = r0 + wm * 64 + ((l >> 4) << 2);
#pragma unroll
    for (int i = 0; i < 4; ++i)
#pragma unroll
        for (int rr = 0; rr < 4; ++rr) {
            const int row = rbase + i * 16 + rr;
            const int s = (row >= bnd0) + (row >= bnd1) + (row >= bnd2);
#pragma unroll
            for (int j = 0; j < 2; ++j) {
                const float e = __expf(acc_a[i][j][rr] + b1c[j]);
                const float ey = e * (acc_v[i][j][rr] + b2c[j]);
#pragma unroll
                for (int s2 = 0; s2 < 4; ++s2) {
                    dpart[s2][j] += (s == s2) ? e : 0.f;
                    ypart[s2][j] += (s == s2) ? ey : 0.f;
                }
            }
        }
    // butterfly over lane bits 4,5 -> sum over the wave's 64 rows
#pragma unroll
    for (int s2 = 0; s2 < 4; ++s2)
#pragma unroll
        for (int j = 0; j < 2; ++j) {
            dpart[s2][j] += __shfl_xor(dpart[s2][j], 16);
            dpart[s2][j] += __shfl_xor(dpart[s2][j], 32);
            ypart[s2][j] += __shfl_xor(ypart[s2][j], 16);
            ypart[s2][j] += __shfl_xor(ypart[s2][j], 32);
        }
    float* red = (float*)&lsA[0];    // [wm][s][col64][2] = 4 KB (staging done)
    if ((l >> 4) == 0) {
#pragma unroll
        for (int s2 = 0; s2 < 4; ++s2)
#pragma unroll
            for (int j = 0; j < 2; ++j) {
                const int colL = wn * 32 + j * 16 + fr;
                red[((wm * 4 + s2) * 64 + colL) * 2 + 0] = dpart[s2][j];
                red[((wm * 4 + s2) * 64 + colL) * 2 + 1] = ypart[s2][j];
            }
    }
    __syncthreads();
#pragma unroll
    for (int k = 0; k < 2; ++k) {
        const int idx = tid * 2 + k;      // 0..511
        const int dy = idx & 1;
        const int colL = (idx >> 1) & 63;
        const int s2 = idx >> 7;
        const float vsum = red[((0 * 4 + s2) * 64 + colL) * 2 + dy] +
                           red[((1 * 4 + s2) * 64 + colL) * 2 + dy];
        pt[((((size_t)(b * 64 + tl)) * 4 + s2) * 512 + et * 64 + colL) * 2 + dy] = vsum;
    }
}

// ---------------- ordered cross-tile combine -> y[b][g][col] ----------------
__global__ __launch_bounds__(256) void combineC(const float* __restrict__ pt,
                                                const int* __restrict__ base,
                                                const int* __restrict__ counts,
                                                const int* __restrict__ fg,
                                                float* __restrict__ y) {
    const int g = blockIdx.x, b = blockIdx.y;
    const int bs = base[g];
    int cnt = counts[g];
    if (cnt == 0) cnt = 1;
    const int t0 = bs >> 7, t1 = (bs + cnt - 1) >> 7;
    for (int c = threadIdx.x; c < 512; c += 256) {
        float d = 0.f, yy = 0.f;
        for (int t = t0; t <= t1; ++t) {
            const int s = g - fg[t];
            if (s >= 0 && s < 4) {
                const float* p = &pt[((((size_t)(b * 64 + t)) * 4 + s) * 512 + c) * 2];
                d += p[0];
                yy += p[1];
            }
        }
        y[((size_t)(b * G_ + g)) * 512 + c] = yy / d;
    }
}

// ---------------- small GEMM: out_small = y @ w3^T + b3 (f32 vector) --------
__global__ __launch_bounds__(256) void gemm3(const float* __restrict__ y,
                                             const float* __restrict__ w3,
                                             const float* __restrict__ b3,
                                             float* __restrict__ out_small) {
    __shared__ float ys[16][68];
    __shared__ float wss[16][68];
    const int m0 = blockIdx.x * 64;
    const int n0 = blockIdx.y * 64;
    const int tid = threadIdx.x;
    const int tr = tid >> 4;
    const int tc = tid & 15;
    const int lrow = tid >> 2;
    const int lk4 = (tid & 3) * 4;

    float acc[4][4] = {};

    for (int k0 = 0; k0 < D_; k0 += 16) {
        float4 yv = *(const float4*)(y + (size_t)(m0 + lrow) * D_ + k0 + lk4);
        float4 wv = *(const float4*)(w3 + (size_t)(n0 + lrow) * D_ + k0 + lk4);
        __syncthreads();
        ys[lk4 + 0][lrow] = yv.x;  ys[lk4 + 1][lrow] = yv.y;
        ys[lk4 + 2][lrow] = yv.z;  ys[lk4 + 3][lrow] = yv.w;
        wss[lk4 + 0][lrow] = wv.x; wss[lk4 + 1][lrow] = wv.y;
        wss[lk4 + 2][lrow] = wv.z; wss[lk4 + 3][lrow] = wv.w;
        __syncthreads();
#pragma unroll
        for (int kk = 0; kk < 16; ++kk) {
            float4 y4 = *(const float4*)&ys[kk][tr * 4];
            float4 w4 = *(const float4*)&wss[kk][tc * 4];
            float ya[4] = {y4.x, y4.y, y4.z, y4.w};
            float wa[4] = {w4.x, w4.y, w4.z, w4.w};
#pragma unroll
            for (int i = 0; i < 4; ++i)
#pragma unroll
                for (int j = 0; j < 4; ++j)
                    acc[i][j] = fmaf(ya[i], wa[j], acc[i][j]);
        }
    }

    float bb[4];
#pragma unroll
    for (int j = 0; j < 4; ++j) bb[j] = b3[n0 + tc * 4 + j];
#pragma unroll
    for (int i = 0; i < 4; ++i) {
        size_t o = (size_t)(m0 + tr * 4 + i) * D_ + n0 + tc * 4;
        float4 r;
        r.x = acc[i][0] + bb[0]; r.y = acc[i][1] + bb[1];
        r.z = acc[i][2] + bb[2]; r.w = acc[i][3] + bb[3];
        *(float4*)(out_small + o) = r;
    }
}

// ---------------- gather group outputs back to rows -------------------------
__global__ __launch_bounds__(256) void gather_out(const int* __restrict__ ids,
                                                  const float* __restrict__ out_small,
                                                  float* __restrict__ out) {
    const int c = blockIdx.x * 256 + threadIdx.x;   // one float4 chunk
    const int per_row = D_ / 4;                     // 128
    const int b = c / (N_ * per_row);
    const int rem = c % (N_ * per_row);
    const int n = rem / per_row;
    const int q = rem % per_row;
    const int g = ids[n];
    float4 val = *(const float4*)(out_small + ((size_t)b * G_ + g) * D_ + q * 4);
    *(float4*)(out + (size_t)c * 4) = val;
}

// ---------------- launcher --------------------------------------------------
extern "C" void kernel_launch(void* const* d_in, const int* in_sizes, int n_in,
                              void* d_out, int out_size, void* d_ws, size_t ws_size,
                              hipStream_t stream) {
    (void)in_sizes; (void)n_in; (void)out_size; (void)ws_size;
    const float* x   = (const float*)d_in[0];
    const int*   ids = (const int*)d_in[1];
    const float* w1  = (const float*)d_in[2];
    const float* b1  = (const float*)d_in[3];
    const float* w2  = (const float*)d_in[4];
    const float* b2  = (const float*)d_in[5];
    const float* w3  = (const float*)d_in[6];
    const float* b3  = (const float*)d_in[7];
    float* out = (float*)d_out;

    float* ws_f = (float*)d_ws;
    unsigned short* xb = (unsigned short*)ws_f;          // 64 MB (permuted bf16 x)
    float* after_xb  = ws_f + 16777216;
    unsigned short* wB = (unsigned short*)after_xb;      // 1 MB
    float* biasB     = after_xb + 262144;                // 4 KB
    float* pt        = biasB + 1024;                     // 8 MB  [b][tl][s4][512][2]
    float* y         = pt + 2097152;                     // 1 MB
    float* out_small = y + 262144;                       // 1 MB
    int*   perm      = (int*)(out_small + 262144);       // 32 KB
    int*   base      = perm + N_;
    int*   counts    = base + G_;
    int*   fg        = counts + G_;

    hipLaunchKernelGGL(build_lists3, dim3(1), dim3(256), 0, stream, ids, counts, base, fg, perm);
    hipLaunchKernelGGL(cast_w, dim3(512), dim3(256), 0, stream, w1, b1, w2, b2, wB, biasB);
    hipLaunchKernelGGL(cast_xp, dim3(2048), dim3(256), 0, stream, x, perm, xb);
    hipLaunchKernelGGL(gemm_fused, dim3(4096), dim3(256), 0, stream,
                       xb, wB, biasB, base, fg, pt);
    hipLaunchKernelGGL(combineC, dim3(G_, B_), dim3(256), 0, stream, pt, base, counts, fg, y);
    hipLaunchKernelGGL(gemm3, dim3(8, 8), dim3(256), 0, stream, y, w3, b3, out_small);
    hipLaunchKernelGGL(gather_out, dim3(32768), dim3(256), 0, stream, ids, out_small, out);
}

// Round 9
// 194.889 us; speedup vs baseline: 1.1962x; 1.1452x over previous
//
#include <hip/hip_runtime.h>
#include <hip/hip_bf16.h>
#include <math.h>

#define B_ 8
#define N_ 8192
#define D_ 512
#define G_ 64
#define M_ (B_ * N_)   // 65536

typedef short bf16x8 __attribute__((ext_vector_type(8)));
typedef float f32x4 __attribute__((ext_vector_type(4)));

__device__ __forceinline__ unsigned short f2bf(float f) {
    __hip_bfloat16 h = __float2bfloat16(f);
    return *reinterpret_cast<unsigned short*>(&h);
}
__device__ __forceinline__ void gload_lds16(const void* g, void* l) {
    __builtin_amdgcn_global_load_lds((const __attribute__((address_space(1))) void*)g,
                                     (__attribute__((address_space(3))) void*)l,
                                     16, 0, 0);
}

// ---------------- permuted cast: xb[b][i][:] = bf16(x[b][perm[i]][:]) -------
__global__ __launch_bounds__(256) void cast_xp(const float* __restrict__ x,
                                               const int* __restrict__ perm,
                                               unsigned short* __restrict__ xb) {
    const int total = M_ * 128;          // one float4 per item
    for (int idx = blockIdx.x * 256 + threadIdx.x; idx < total;
         idx += gridDim.x * 256) {
        const int row = idx >> 7;        // b*8192 + permuted slot
        const int q = (idx & 127) * 4;
        const int b = row >> 13;
        const int i = row & 8191;
        const float* src = x + (((size_t)(b << 13) + perm[i]) << 9) + q;
        float4 f = *(const float4*)src;
        ushort4 u;
        u.x = f2bf(f.x); u.y = f2bf(f.y); u.z = f2bf(f.z); u.w = f2bf(f.w);
        *(ushort4*)(xb + ((size_t)row << 9) + q) = u;
    }
}

// ---------------- cast kernel (weights) -------------------------------------
__global__ __launch_bounds__(256) void cast_w(const float* __restrict__ w1,
                                              const float* __restrict__ b1,
                                              const float* __restrict__ w2,
                                              const float* __restrict__ b2,
                                              unsigned short* __restrict__ wB,
                                              float* __restrict__ biasB) {
    int t = blockIdx.x * 256 + threadIdx.x;   // one float4
    int idx = t * 4;
    int row = idx >> 9;
    int col = idx & 511;
    const float* src = (row < 512) ? (w1 + (size_t)row * 512 + col)
                                   : (w2 + (size_t)(row - 512) * 512 + col);
    float4 f = *(const float4*)src;
    ushort4 u;
    u.x = f2bf(f.x); u.y = f2bf(f.y); u.z = f2bf(f.z); u.w = f2bf(f.w);
    *(ushort4*)(wB + idx) = u;
    if (t < 1024) biasB[t] = (t < 512) ? b1[t] : b2[t - 512];
}

// ---------------- parallel group-sorted permutation -------------------------
// bl_hist: one block per group; strip counts + per-strip exclusive offsets.
__global__ __launch_bounds__(256) void bl_hist(const int* __restrict__ ids,
                                               int* __restrict__ counts,
                                               int* __restrict__ stripbase) {
    __shared__ int sid[N_];       // 32 KB
    __shared__ int sc[256];
    const int g = blockIdx.x;
    const int t = threadIdx.x;
    for (int i = t; i < N_; i += 256) sid[i] = ids[i];
    __syncthreads();
    int c = 0;
    const int nb = t * 32;
#pragma unroll 8
    for (int k = 0; k < 32; ++k) c += (sid[nb + k] == g) ? 1 : 0;
    sc[t] = c;
    __syncthreads();
    if (t == 0) {
        int run = 0;
        for (int i = 0; i < 256; ++i) { int v = sc[i]; sc[i] = run; run += v; }
        counts[g] = run;
    }
    __syncthreads();
    stripbase[g * 256 + t] = sc[t];
}

// bl_emit: one block per group; emits perm (strip-major, in-strip order).
// Block 0 additionally writes base[] and fg[].
__global__ __launch_bounds__(256) void bl_emit(const int* __restrict__ ids,
                                               const int* __restrict__ counts,
                                               const int* __restrict__ stripbase,
                                               int* __restrict__ baseO,
                                               int* __restrict__ fgO,
                                               int* __restrict__ perm) {
    __shared__ int sid[N_];
    __shared__ int sb[G_ + 1];
    __shared__ int sbs;
    const int g = blockIdx.x;
    const int t = threadIdx.x;
    for (int i = t; i < N_; i += 256) sid[i] = ids[i];
    if (t == 0) {
        int a = 0;
        for (int gg = 0; gg < G_; ++gg) { sb[gg] = a; a += counts[gg]; }
        sb[G_] = a;
        sbs = sb[g];
    }
    __syncthreads();
    if (g == 0 && t < G_) {
        baseO[t] = sb[t];
        const int row = t * 128;
        int gg = 0;
        while (gg + 1 < G_ && sb[gg + 1] <= row) ++gg;
        fgO[t] = gg;
    }
    int pos = sbs + stripbase[g * 256 + t];
    const int nb = t * 32;
    for (int k = 0; k < 32; ++k)
        if (sid[nb + k] == g) perm[pos++] = nb + k;
}

// ---------------- fused 256x256 MFMA GEMM + segment softmax-aggregate -------
// BM=256 permuted rows, paired BN = 128 a-cols + 128 v-cols, BK=64, 8 waves
// (2 wm x 4 wn), 128 KB dynamic LDS (full-K-tile double buffer), XOR-swizzled
// staging via global_load_lds + pre-swizzled source cols. Wave (wm,wn) owns
// 128 rows (= one 128-row tl) x (32 a-cols paired with 32 v-cols).
__global__ __launch_bounds__(512, 2) void gemm_fused(const unsigned short* __restrict__ xb,
                                                     const unsigned short* __restrict__ wB,
                                                     const float* __restrict__ biasB,
                                                     const int* __restrict__ base,
                                                     const int* __restrict__ fg,
                                                     float* __restrict__ pt) {
    extern __shared__ unsigned short smem[];
    unsigned short* lsA = smem;             // [2][256*64]  64 KB
    unsigned short* lsB = smem + 32768;     // [2][256*64]  64 KB

    // swizzle: 4 nt-blocks sharing an A-tile are consecutive mod-8 (same XCD)
    const int o  = blockIdx.x;               // 0..1023
    const int mt = (o & 7) + ((o >> 5) << 3);   // 0..255
    const int nt = (o >> 3) & 3;                // 0..3
    const int b  = mt >> 5;                     // batch
    const int tlb = (mt & 31) * 2;              // first 128-row tile of block
    const int c0 = nt * 128;                    // a/v col base

    const int tid = threadIdx.x;
    const int l = tid & 63;
    const int w = tid >> 6;               // wave 0..7
    const int wm = w >> 2;                // 0..1  (row half)
    const int wn = w & 3;                 // 0..3  (col quarter)
    const int lr = l >> 3;                // staging row-in-chunk
    const int lslot = l & 7;
    const int fr = l & 15;
    const int kq = l >> 4;                // 0..3
    const int scol = 8 * (lslot ^ lr);    // pre-swizzled source col (elems)

    f32x4 acc[8][4];
#pragma unroll
    for (int i = 0; i < 8; ++i)
#pragma unroll
        for (int j = 0; j < 4; ++j) acc[i][j] = (f32x4){0.f, 0.f, 0.f, 0.f};

    const size_t abase = (((size_t)b << 13) + (size_t)(mt & 31) * 256) << 9;

    auto stageT = [&](int buf, int kt) {
#pragma unroll
        for (int q = 0; q < 4; ++q) {              // A: 32 chunks of 8 rows
            const int c = w * 4 + q;
            const int row = c * 8 + lr;
            gload_lds16(xb + abase + ((size_t)row << 9) + kt + scol,
                        lsA + buf * 16384 + c * 512);
        }
#pragma unroll
        for (int q = 0; q < 4; ++q) {              // B: 32 chunks of 8 rows
            const int c = w * 4 + q;
            // panel row -> source row in wB[1024][512]
            const int srcrow = ((c >> 2) & 1) * 512 + c0 + (c >> 3) * 32
                             + (c & 3) * 8 + lr;
            gload_lds16(wB + ((size_t)srcrow << 9) + kt + scol,
                        lsB + buf * 16384 + c * 512);
        }
    };

    stageT(0, 0);
    __syncthreads();
    int cur = 0;
    for (int t8 = 0; t8 < 8; ++t8) {
        if (t8 < 7) stageT(cur ^ 1, (t8 + 1) * 64);     // async prefetch
        const unsigned short* pA = lsA + cur * 16384;
        const unsigned short* pB = lsB + cur * 16384;
        const int ib0 = 8 * (kq ^ (fr & 7));            // ks=0 swizzled elems
        const int ib1 = 8 * ((4 + kq) ^ (fr & 7));      // ks=1
        bf16x8 bq0[4], bq1[4];
#pragma unroll
        for (int j = 0; j < 4; ++j) {
            const int brow = (wn * 64 + j * 16 + fr) * 64;
            bq0[j] = *(const bf16x8*)&pB[brow + ib0];
            bq1[j] = *(const bf16x8*)&pB[brow + ib1];
        }
#pragma unroll
        for (int i = 0; i < 8; ++i) {
            const int arow = (wm * 128 + i * 16 + fr) * 64;
            bf16x8 a0 = *(const bf16x8*)&pA[arow + ib0];
            bf16x8 a1 = *(const bf16x8*)&pA[arow + ib1];
#pragma unroll
            for (int j = 0; j < 4; ++j)
                acc[i][j] = __builtin_amdgcn_mfma_f32_16x16x32_bf16(a0, bq0[j], acc[i][j], 0, 0, 0);
#pragma unroll
            for (int j = 0; j < 4; ++j)
                acc[i][j] = __builtin_amdgcn_mfma_f32_16x16x32_bf16(a1, bq1[j], acc[i][j], 0, 0, 0);
        }
        __syncthreads();     // drains ds reads + prefetch vmcnt
        cur ^= 1;
    }

    // ---- epilogue: exp + per-wave segment reduce (wave owns full tl) ----
    const int tl = tlb + wm;
    const int fg0 = fg[tl];
    const int bnd0 = (fg0 + 1 < G_) ? base[fg0 + 1] : (1 << 30);
    const int bnd1 = (fg0 + 2 < G_) ? base[fg0 + 2] : (1 << 30);
    const int bnd2 = (fg0 + 3 < G_) ? base[fg0 + 3] : (1 << 30);
    float b1c[2], b2c[2];
#pragma unroll
    for (int j = 0; j < 2; ++j) {
        const int col = c0 + wn * 32 + j * 16 + fr;
        b1c[j] = biasB[col];
        b2c[j] = biasB[512 + col];
    }
    float dp[4][2] = {}, yp[4][2] = {};
    const int rbase = tl * 128 + kq * 4;
#pragma unroll
    for (int i = 0; i < 8; ++i)
#pragma unroll
        for (int rr = 0; rr < 4; ++rr) {
            const int row = rbase + i * 16 + rr;
            const int s = (row >= bnd0) + (row >= bnd1) + (row >= bnd2);
#pragma unroll
            for (int j = 0; j < 2; ++j) {
                const float e = __expf(acc[i][j][rr] + b1c[j]);
                const float ey = e * (acc[i][j + 2][rr] + b2c[j]);
#pragma unroll
                for (int s2 = 0; s2 < 4; ++s2) {
                    dp[s2][j] += (s == s2) ? e : 0.f;
                    yp[s2][j] += (s == s2) ? ey : 0.f;
                }
            }
        }
#pragma unroll
    for (int s2 = 0; s2 < 4; ++s2)
#pragma unroll
        for (int j = 0; j < 2; ++j) {
            dp[s2][j] += __shfl_xor(dp[s2][j], 16);
            dp[s2][j] += __shfl_xor(dp[s2][j], 32);
            yp[s2][j] += __shfl_xor(yp[s2][j], 16);
            yp[s2][j] += __shfl_xor(yp[s2][j], 32);
        }
    if (kq == 0) {
#pragma unroll
        for (int s2 = 0; s2 < 4; ++s2)
#pragma unroll
            for (int j = 0; j < 2; ++j) {
                const int colp = c0 + wn * 32 + j * 16 + fr;
                float2 v = make_float2(dp[s2][j], yp[s2][j]);
                *(float2*)&pt[(((size_t)(b * 64 + tl) * 4 + s2) * 512 + colp) * 2] = v;
            }
    }
}

// ---------------- ordered cross-tile combine -> y[b][g][col] ----------------
__global__ __launch_bounds__(256) void combineC(const float* __restrict__ pt,
                                                const int* __restrict__ base,
                                                const int* __restrict__ counts,
                                                const int* __restrict__ fg,
                                                float* __restrict__ y) {
    const int g = blockIdx.x, b = blockIdx.y;
    const int bs = base[g];
    int cnt = counts[g];
    if (cnt == 0) cnt = 1;
    const int t0 = bs >> 7, t1 = (bs + cnt - 1) >> 7;
    for (int c = threadIdx.x; c < 512; c += 256) {
        float d = 0.f, yy = 0.f;
        for (int t = t0; t <= t1; ++t) {
            const int s = g - fg[t];
            if (s >= 0 && s < 4) {
                const float* p = &pt[((((size_t)(b * 64 + t)) * 4 + s) * 512 + c) * 2];
                d += p[0];
                yy += p[1];
            }
        }
        y[((size_t)(b * G_ + g)) * 512 + c] = yy / d;
    }
}

// ---------------- small GEMM: out_small = y @ w3^T + b3 (f32 vector) --------
__global__ __launch_bounds__(256) void gemm3(const float* __restrict__ y,
                                             const float* __restrict__ w3,
                                             const float* __restrict__ b3,
                                             float* __restrict__ out_small) {
    __shared__ float ys[16][68];
    __shared__ float wss[16][68];
    const int m0 = blockIdx.x * 64;
    const int n0 = blockIdx.y * 64;
    const int tid = threadIdx.x;
    const int tr = tid >> 4;
    const int tc = tid & 15;
    const int lrow = tid >> 2;
    const int lk4 = (tid & 3) * 4;

    float acc[4][4] = {};

    for (int k0 = 0; k0 < D_; k0 += 16) {
        float4 yv = *(const float4*)(y + (size_t)(m0 + lrow) * D_ + k0 + lk4);
        float4 wv = *(const float4*)(w3 + (size_t)(n0 + lrow) * D_ + k0 + lk4);
        __syncthreads();
        ys[lk4 + 0][lrow] = yv.x;  ys[lk4 + 1][lrow] = yv.y;
        ys[lk4 + 2][lrow] = yv.z;  ys[lk4 + 3][lrow] = yv.w;
        wss[lk4 + 0][lrow] = wv.x; wss[lk4 + 1][lrow] = wv.y;
        wss[lk4 + 2][lrow] = wv.z; wss[lk4 + 3][lrow] = wv.w;
        __syncthreads();
#pragma unroll
        for (int kk = 0; kk < 16; ++kk) {
            float4 y4 = *(const float4*)&ys[kk][tr * 4];
            float4 w4 = *(const float4*)&wss[kk][tc * 4];
            float ya[4] = {y4.x, y4.y, y4.z, y4.w};
            float wa[4] = {w4.x, w4.y, w4.z, w4.w};
#pragma unroll
            for (int i = 0; i < 4; ++i)
#pragma unroll
                for (int j = 0; j < 4; ++j)
                    acc[i][j] = fmaf(ya[i], wa[j], acc[i][j]);
        }
    }

    float bb[4];
#pragma unroll
    for (int j = 0; j < 4; ++j) bb[j] = b3[n0 + tc * 4 + j];
#pragma unroll
    for (int i = 0; i < 4; ++i) {
        size_t o = (size_t)(m0 + tr * 4 + i) * D_ + n0 + tc * 4;
        float4 r;
        r.x = acc[i][0] + bb[0]; r.y = acc[i][1] + bb[1];
        r.z = acc[i][2] + bb[2]; r.w = acc[i][3] + bb[3];
        *(float4*)(out_small + o) = r;
    }
}

// ---------------- gather group outputs back to rows -------------------------
__global__ __launch_bounds__(256) void gather_out(const int* __restrict__ ids,
                                                  const float* __restrict__ out_small,
                                                  float* __restrict__ out) {
    const int c = blockIdx.x * 256 + threadIdx.x;   // one float4 chunk
    const int per_row = D_ / 4;                     // 128
    const int b = c / (N_ * per_row);
    const int rem = c % (N_ * per_row);
    const int n = rem / per_row;
    const int q = rem % per_row;
    const int g = ids[n];
    float4 val = *(const float4*)(out_small + ((size_t)b * G_ + g) * D_ + q * 4);
    *(float4*)(out + (size_t)c * 4) = val;
}

// ---------------- launcher --------------------------------------------------
extern "C" void kernel_launch(void* const* d_in, const int* in_sizes, int n_in,
                              void* d_out, int out_size, void* d_ws, size_t ws_size,
                              hipStream_t stream) {
    (void)in_sizes; (void)n_in; (void)out_size; (void)ws_size;
    const float* x   = (const float*)d_in[0];
    const int*   ids = (const int*)d_in[1];
    const float* w1  = (const float*)d_in[2];
    const float* b1  = (const float*)d_in[3];
    const float* w2  = (const float*)d_in[4];
    const float* b2  = (const float*)d_in[5];
    const float* w3  = (const float*)d_in[6];
    const float* b3  = (const float*)d_in[7];
    float* out = (float*)d_out;

    float* ws_f = (float*)d_ws;
    unsigned short* xb = (unsigned short*)ws_f;          // 64 MB (permuted bf16 x)
    float* after_xb  = ws_f + 16777216;
    unsigned short* wB = (unsigned short*)after_xb;      // 1 MB
    float* biasB     = after_xb + 262144;                // 4 KB
    float* pt        = biasB + 1024;                     // 8 MB  [b*64+tl][4][512][2]
    float* y         = pt + 2097152;                     // 1 MB
    float* out_small = y + 262144;                       // 1 MB
    int*   perm      = (int*)(out_small + 262144);       // 32 KB
    int*   base      = perm + N_;
    int*   counts    = base + G_;
    int*   fg        = counts + G_;
    int*   stripbase = fg + G_;                          // 64 KB

    hipFuncSetAttribute((const void*)gemm_fused,
                        hipFuncAttributeMaxDynamicSharedMemorySize, 131072);

    hipLaunchKernelGGL(bl_hist, dim3(G_), dim3(256), 0, stream, ids, counts, stripbase);
    hipLaunchKernelGGL(bl_emit, dim3(G_), dim3(256), 0, stream,
                       ids, counts, stripbase, base, fg, perm);
    hipLaunchKernelGGL(cast_w, dim3(512), dim3(256), 0, stream, w1, b1, w2, b2, wB, biasB);
    hipLaunchKernelGGL(cast_xp, dim3(2048), dim3(256), 0, stream, x, perm, xb);
    hipLaunchKernelGGL(gemm_fused, dim3(1024), dim3(512), 131072, stream,
                       xb, wB, biasB, base, fg, pt);
    hipLaunchKernelGGL(combineC, dim3(G_, B_), dim3(256), 0, stream, pt, base, counts, fg, y);
    hipLaunchKernelGGL(gemm3, dim3(8, 8), dim3(256), 0, stream, y, w3, b3, out_small);
    hipLaunchKernelGGL(gather_out, dim3(32768), dim3(256), 0, stream, ids, out_small, out);
}